// Round 6
// baseline (48.294 us; speedup 1.0000x reference)
//
#include <hip/hip_runtime.h>
#include <math.h>

#define LN_EPS 1e-5f

typedef _Float16 f16;
typedef _Float16 f16x8 __attribute__((ext_vector_type(8)));
typedef _Float16 f16x2 __attribute__((ext_vector_type(2)));
typedef float f32x4 __attribute__((ext_vector_type(4)));
typedef unsigned long long ull;

constexpr int DC = 16;
constexpr int K = 8192;
constexpr int NTOK = 16384;          // 8*2048
constexpr int KSPLIT = 16;
constexpr int KCHUNK = K / KSPLIT;   // 512 codes per (block.y) split
constexpr int JT = 8;                // token-tiles per wave (argmin)
constexpr float SCALE = 16384.f;     // SH(256) * SW/SC(64), exact powers of 2
constexpr float EPS_S = LN_EPS * SCALE * SCALE;  // eps in scaled-variance units
constexpr int XP = 516;              // xs row pitch (floats)

// ---------------------------------------------------------------------------
// Kernel 1 (fused): blocks [0,1024) projection+LayerNorm -> hB fragments
// (MFMA-based; W lives in 32 VGPRs/wave as hi/lo A-frags, K split across the
// 4 waves, partials combined via LDS). Blocks [1024,1152): codebook -> cbA
// fragments + biased c2.
//
// Frag convention per 16-wide tile (16x16x32_f16): lane l holds 8 halves,
// slots s=(l>>4)*8+p. s<16 -> hi(value dim s), s>=16 -> lo(dim s-16).
// Exact product: mfma(a,b1) + mfma(a,b2) where b2 is b1 with lane-groups
// swapped ([lo|hi]) covers all four hi/lo cross terms.
// ---------------------------------------------------------------------------
__global__ __launch_bounds__(256, 4) void prep_proj(
    const float* __restrict__ x, const float* __restrict__ wq,
    const float* __restrict__ cb, f16* __restrict__ hB,
    f16* __restrict__ cbA, float* __restrict__ c2s) {
  const int tid = threadIdx.x;

  if (blockIdx.x >= NTOK / 16) {
    // ---- codebook prep: 128 blocks, 4 code-tiles each ----
    const int ti = tid >> 6;
    const int l = tid & 63;
    const int ct = (blockIdx.x - NTOK / 16) * 4 + ti;
    const int code = ct * 16 + (l & 15);
    const int g = l >> 4;

    const float* row = cb + (size_t)code * DC + (g & 1) * 8;
    f32x4 v0 = *(const f32x4*)row;
    f32x4 v1 = *(const f32x4*)(row + 4);
    float vv[8] = {v0[0], v0[1], v0[2], v0[3], v1[0], v1[1], v1[2], v1[3]};

    f16x8 r;
#pragma unroll
    for (int p = 0; p < 8; ++p) {
      float cc = -128.f * vv[p];   // (-2*cb) * 64, exact pow2 scaling
      f16 hh = (f16)cc;
      r[p] = (g < 2) ? hh : (f16)(cc - (float)hh);
    }
    *(f16x8*)(cbA + ((size_t)ct * 64 + l) * 8) = r;

    if (g == 0) {
      const f32x4* rw = (const f32x4*)(cb + (size_t)code * DC);
      f32x4 a0 = rw[0], a1 = rw[1], a2 = rw[2], a3 = rw[3];
      float s = 0.f;
#pragma unroll
      for (int p = 0; p < 4; ++p)
        s += a0[p] * a0[p] + a1[p] * a1[p] + a2[p] * a2[p] + a3[p] * a3[p];
      c2s[code] = (s + 16.5f) * SCALE;   // +16.5 > h2=16 keeps dist > 0
    }
    return;
  }

  // ---- projection + LayerNorm: 1024 blocks, 16 tokens (one B-tile) ----
  __shared__ float xs[16 * XP];        // ~33 KB staged x (coalesced fill)
  __shared__ float comb[4 * 16 * 20];  // 5 KB K-split partial C tiles
  __shared__ float hsm[16][17];        // LN'd h, [token][dim]

  // stage x: 8 float4 per thread, bursty + coalesced (saturates HBM)
  const float4* xg = (const float4*)(x + (size_t)blockIdx.x * (16 * 512));
#pragma unroll
  for (int i = 0; i < 8; ++i) {
    int idx = tid + 256 * i;           // float4 index 0..2047
    int tok = idx >> 7;
    int d4 = idx & 127;
    *(float4*)&xs[tok * XP + d4 * 4] = xg[idx];
  }

  // build this wave's 8 W A-frags (K-quarter) from global w while the
  // LDS staging drains. a-frag: row = lane&15 = c_out, slots per convention.
  const int w = tid >> 6;
  const int lane = tid & 63;
  const int g = lane >> 4;
  const int c_out = lane & 15;
  const int doff = (g & 1) * 8;
  f16x8 aw[8];
#pragma unroll
  for (int st = 0; st < 8; ++st) {
    const int step = w * 8 + st;
    const float* wp = wq + (size_t)c_out * 512 + step * 16 + doff;
    f32x4 u0 = *(const f32x4*)wp;
    f32x4 u1 = *(const f32x4*)(wp + 4);
    float v[8] = {u0[0], u0[1], u0[2], u0[3], u1[0], u1[1], u1[2], u1[3]};
    f16x8 r;
#pragma unroll
    for (int p = 0; p < 8; ++p) {
      float f = v[p] * 64.f;           // exact pow2 scale
      f16 h1 = (f16)f;
      r[p] = (g < 2) ? h1 : (f16)(f - (float)h1);
    }
    aw[st] = r;
  }
  __syncthreads();

  // MFMA over this wave's K-quarter: 8 steps x 2 mfma (exact hi/lo)
  f32x4 acc = {0.f, 0.f, 0.f, 0.f};
  const int tok = lane & 15;           // B col = token
#pragma unroll
  for (int st = 0; st < 8; ++st) {
    const int step = w * 8 + st;
    const float* xp = &xs[tok * XP + step * 16 + doff];
    f32x4 u0 = *(const f32x4*)xp;
    f32x4 u1 = *(const f32x4*)(xp + 4);
    float v[8] = {u0[0], u0[1], u0[2], u0[3], u1[0], u1[1], u1[2], u1[3]};
    f16x8 bh, bl;
#pragma unroll
    for (int p = 0; p < 8; ++p) {
      float f = v[p] * 256.f;          // exact pow2 scale
      f16 h1 = (f16)f;
      bh[p] = h1;
      bl[p] = (f16)(f - (float)h1);
    }
    f16x8 b1 = (g < 2) ? bh : bl;      // [hi|lo] by lane-group
    f16x8 b2 = (g < 2) ? bl : bh;      // [lo|hi]
    acc = __builtin_amdgcn_mfma_f32_16x16x32_f16(aw[st], b1, acc, 0, 0, 0);
    acc = __builtin_amdgcn_mfma_f32_16x16x32_f16(aw[st], b2, acc, 0, 0, 0);
  }

  // write partial C tile: lane holds C[row=g*4+r][col=tok]
  *(f32x4*)&comb[w * 320 + tok * 20 + g * 4] = acc;
  __syncthreads();

  // combine K-split partials + LayerNorm (on scaled values; exact ratio)
  const int tokL = tid >> 4;
  const int cL = tid & 15;
  float hv = (comb[0 * 320 + tokL * 20 + cL] + comb[1 * 320 + tokL * 20 + cL]) +
             (comb[2 * 320 + tokL * 20 + cL] + comb[3 * 320 + tokL * 20 + cL]);

  float s = hv;
  s += __shfl_xor(s, 1, 16);
  s += __shfl_xor(s, 2, 16);
  s += __shfl_xor(s, 4, 16);
  s += __shfl_xor(s, 8, 16);
  float mu = s * (1.f / 16.f);
  float diff = hv - mu;
  float v2 = diff * diff;
  v2 += __shfl_xor(v2, 1, 16);
  v2 += __shfl_xor(v2, 2, 16);
  v2 += __shfl_xor(v2, 4, 16);
  v2 += __shfl_xor(v2, 8, 16);
  float var = v2 * (1.f / 16.f);
  hsm[tokL][cL] = diff / sqrtf(var + EPS_S);   // == (h-mu)/sqrt(var+eps)
  __syncthreads();

  // emit B fragment: thread -> (lane l = tid>>2, pair q = tid&3)
  const int le = tid >> 2;
  const int q = tid & 3;
  const int col = le & 15;
  const int ge = le >> 4;
  const int s0 = ge * 8 + q * 2;
  f16x2 u;
#pragma unroll
  for (int e = 0; e < 2; ++e) {
    int sE = s0 + e;
    int d = sE & 15;
    float f = hsm[col][d] * 256.f;     // exact pow2 scale
    f16 hh = (f16)f;
    u[e] = (sE < 16) ? hh : (f16)(f - (float)hh);
  }
  *(f16x2*)(hB + ((size_t)blockIdx.x * 64 + le) * 8 + q * 2) = u;
}

// ---------------------------------------------------------------------------
// Kernel 2: MFMA argmin, no LDS, no barriers. Grid (32, KSPLIT=16) = 512
// blocks -> 2 blocks/CU (2 waves/SIMD), 32 t-iters/wave (prologue amortized
// 2x vs KSPLIT=32). Wave owns JT=8 token-tiles (b1/b2 in regs); codebook
// fragments streamed straight from L2 (512 KB, resident). acc =
// mfma(a,b1,c2); acc = mfma(a,b2,acc) -> exact (hi+lo)x(hi+lo).
// ---------------------------------------------------------------------------
__global__ __launch_bounds__(256, 4) void argmin_mfma(
    const f16* __restrict__ cbA, const float* __restrict__ c2s,
    const f16* __restrict__ hB, ull* __restrict__ pk) {
  const int tid = threadIdx.x;
  const int w = tid >> 6;
  const int lane = tid & 63;
  const int kt0 = blockIdx.y * (KCHUNK / 16);  // first code-tile of split
  const int tt0 = blockIdx.x * (4 * JT) + w * JT;

  // B fragments first (long-latency, independent); b2 = b1 at lane^32
  f16x8 b1[JT], b2[JT];
#pragma unroll
  for (int j = 0; j < JT; ++j) {
    const f16* p = hB + ((size_t)(tt0 + j) * 64) * 8;
    b1[j] = *(const f16x8*)&p[lane * 8];
    b2[j] = *(const f16x8*)&p[(lane ^ 32) * 8];
  }

  float best[JT];
  int bidx[JT];
#pragma unroll
  for (int j = 0; j < JT; ++j) {
    best[j] = 3.0e38f;
    bidx[j] = 0;
  }

  const int lkoff = (lane >> 4) * 4;
#pragma unroll 2
  for (int t = 0; t < KCHUNK / 16; ++t) {
    f16x8 a = *(const f16x8*)&cbA[((size_t)(kt0 + t) * 64 + lane) * 8];
    const int kbase = blockIdx.y * KCHUNK + t * 16;
    f32x4 c2v = *(const f32x4*)&c2s[kbase + lkoff];
    const int ib = kbase + lkoff;
#pragma unroll
    for (int j = 0; j < JT; ++j) {
      f32x4 acc =
          __builtin_amdgcn_mfma_f32_16x16x32_f16(a, b1[j], c2v, 0, 0, 0);
      acc = __builtin_amdgcn_mfma_f32_16x16x32_f16(a, b2[j], acc, 0, 0, 0);
#pragma unroll
      for (int r = 0; r < 4; ++r) {
        bool lt = acc[r] < best[j];     // strict <, ascending k order
        best[j] = lt ? acc[r] : best[j];
        bidx[j] = lt ? (ib + r) : bidx[j];
      }
    }
  }

  // merge the 4 lane-groups (rows) per token column, store per-split key
#pragma unroll
  for (int j = 0; j < JT; ++j) {
    float d = best[j];
    int ix = bidx[j];
#pragma unroll
    for (int off = 16; off <= 32; off <<= 1) {
      float od = __shfl_xor(d, off);
      int oi = __shfl_xor(ix, off);
      bool take = (od < d) || (od == d && oi < ix);
      d = take ? od : d;
      ix = take ? oi : ix;
    }
    d = fmaxf(d, 0.f);  // keep sign bit clear for monotone bit-packing
    if (lane < 16) {
      int token = (tt0 + j) * 16 + lane;
      ull key = ((ull)__float_as_uint(d) << 32) | (unsigned)ix;
      pk[(size_t)token * KSPLIT + blockIdx.y] = key;
    }
  }
}

// ---------------------------------------------------------------------------
// Kernel 3: per-token u64-min over KSPLIT packed keys (dist-major, lowest
// index on ties -> numpy argmin). 128 B contiguous per thread.
// ---------------------------------------------------------------------------
__global__ __launch_bounds__(256) void finalize(const ull* __restrict__ pk,
                                                int* __restrict__ out) {
  int t = blockIdx.x * 256 + threadIdx.x;
  const ull* row = pk + (size_t)t * KSPLIT;
  ull best = row[0];
#pragma unroll
  for (int s = 1; s < KSPLIT; ++s) {
    ull k2 = row[s];
    best = (k2 < best) ? k2 : best;
  }
  out[t] = (int)(unsigned)(best & 0xFFFFFFFFull);
}

// ---------------------------------------------------------------------------
extern "C" void kernel_launch(void* const* d_in, const int* in_sizes, int n_in,
                              void* d_out, int out_size, void* d_ws,
                              size_t ws_size, hipStream_t stream) {
  const float* x = (const float*)d_in[0];    // (8,2048,512)
  const float* w = (const float*)d_in[1];    // (16,512)
  const float* cb = (const float*)d_in[2];   // (8192,16)

  f16* cbA = (f16*)d_ws;                         // 8192*32 halves = 512 KB
  float* c2s = (float*)(cbA + (size_t)K * 32);   // 32 KB
  f16* hB = (f16*)(c2s + K);                     // 16384*32 halves = 1 MB
  ull* pk = (ull*)(hB + (size_t)NTOK * 32);      // NTOK*KSPLIT*8 = 2 MB

  prep_proj<<<NTOK / 16 + K / 64, 256, 0, stream>>>(x, w, cb, hB, cbA, c2s);
  argmin_mfma<<<dim3(NTOK / (64 * JT), KSPLIT), 256, 0, stream>>>(cbA, c2s,
                                                                  hB, pk);
  finalize<<<NTOK / 256, 256, 0, stream>>>(pk, (int*)d_out);
}

// Round 7
// 45.356 us; speedup vs baseline: 1.0648x; 1.0648x over previous
//
#include <hip/hip_runtime.h>
#include <math.h>

#define LN_EPS 1e-5f

typedef _Float16 f16;
typedef _Float16 f16x8 __attribute__((ext_vector_type(8)));
typedef float f32x4 __attribute__((ext_vector_type(4)));

constexpr int DC = 16;
constexpr int K = 8192;
constexpr int NTOK = 16384;        // 8*2048
constexpr int D = 512;
constexpr float SCALE = 16384.f;   // 256 * 64, exact powers of 2
constexpr float EPS_S = LN_EPS * SCALE * SCALE;

// ---------------------------------------------------------------------------
// K1: codebook -> MFMA-A fragments (fp16 hi/lo, x(-128)) + biased c2.
// Frag per 16-code tile: lane l holds 8 halves, slots s=(l>>4)*8+p;
// s<16 -> hi(dim s), s>=16 -> lo(dim s-16). (proven rounds 2-6)
// ---------------------------------------------------------------------------
__global__ __launch_bounds__(256) void prep_cb(const float* __restrict__ cb,
                                               f16* __restrict__ cbA,
                                               float* __restrict__ c2s) {
  const int tid = threadIdx.x;
  const int ti = tid >> 6;
  const int l = tid & 63;
  const int ct = blockIdx.x * 4 + ti;
  const int code = ct * 16 + (l & 15);
  const int g = l >> 4;

  const float* row = cb + (size_t)code * DC + (g & 1) * 8;
  f32x4 v0 = *(const f32x4*)row;
  f32x4 v1 = *(const f32x4*)(row + 4);
  float vv[8] = {v0[0], v0[1], v0[2], v0[3], v1[0], v1[1], v1[2], v1[3]};

  f16x8 r;
#pragma unroll
  for (int p = 0; p < 8; ++p) {
    float cc = -128.f * vv[p];
    f16 hh = (f16)cc;
    r[p] = (g < 2) ? hh : (f16)(cc - (float)hh);
  }
  *(f16x8*)(cbA + ((size_t)ct * 64 + l) * 8) = r;

  if (g == 0) {
    const f32x4* rw = (const f32x4*)(cb + (size_t)code * DC);
    f32x4 a0 = rw[0], a1 = rw[1], a2 = rw[2], a3 = rw[3];
    float s = 0.f;
#pragma unroll
    for (int p = 0; p < 4; ++p)
      s += a0[p] * a0[p] + a1[p] * a1[p] + a2[p] * a2[p] + a3[p] * a3[p];
    c2s[code] = (s + 16.5f) * SCALE;
  }
}

// ---------------------------------------------------------------------------
// K2: fused proj+LN+argmin. 256 blocks x 1024 thr (1/CU, 4 waves/SIMD).
// Block owns 64 tokens end-to-end; h never leaves the block.
// Phase A: wave (j=w&3 tile, dq=w>>2 D-quarter): W as A-frags (aw[8], x64),
//   x read direct from global (64B sectors), b hi/lo x256, 16 MFMA ->
//   partial C in comb; LN via width-16 shfl on scaled values (EPS_S).
// Phase B: wave w sweeps codes [w*512,(w+1)*512) for all 4 tiles (JT=4).
//   Deferred index: per tile-iter track (min-of-4, tag=t*4+g) only (5 VALU
//   vs 12). Merge lane-groups/waves ordered by k; 4-candidate group
//   disambiguated by exact scalar recompute. Result straight to d_out.
// ---------------------------------------------------------------------------
__global__ __launch_bounds__(1024, 4) void fused(
    const float* __restrict__ x, const float* __restrict__ wq,
    const float* __restrict__ cb, const f16* __restrict__ cbA,
    const float* __restrict__ c2s, int* __restrict__ out) {
  __shared__ float comb[16 * 320];   // 20 KB  [w=dq*4+j][tok16 pitch20]
  __shared__ float hsm[64][17];      // 4.4 KB LN'd h (unscaled)
  __shared__ float fin_d[16][64];    // 4 KB  per-q best dist
  __shared__ int fin_t[16][64];      // 4 KB  per-q packed (t,g)

  const int tid = threadIdx.x;
  const int w = tid >> 6;
  const int lane = tid & 63;
  const int g = lane >> 4;
  const int col = lane & 15;
  const int doff = (g & 1) * 8;
  const int tb = blockIdx.x * 64;

  // ---------------- phase A: projection ----------------
  const int j = w & 3;
  const int dq = w >> 2;

  f16x8 aw[8];
#pragma unroll
  for (int st = 0; st < 8; ++st) {
    const int step = dq * 8 + st;
    const float* wp = wq + (size_t)col * D + step * 16 + doff;  // c_out = col
    f32x4 u0 = *(const f32x4*)wp;
    f32x4 u1 = *(const f32x4*)(wp + 4);
    float v[8] = {u0[0], u0[1], u0[2], u0[3], u1[0], u1[1], u1[2], u1[3]};
    f16x8 r;
#pragma unroll
    for (int p = 0; p < 8; ++p) {
      float f = v[p] * 64.f;
      f16 h1 = (f16)f;
      r[p] = (g < 2) ? h1 : (f16)(f - (float)h1);
    }
    aw[st] = r;
  }

  f32x4 acc = {0.f, 0.f, 0.f, 0.f};
  const float* xrow = x + (size_t)(tb + j * 16 + col) * D;
#pragma unroll
  for (int st = 0; st < 8; ++st) {
    const int step = dq * 8 + st;
    const float* xp = xrow + step * 16 + doff;
    f32x4 u0 = *(const f32x4*)xp;
    f32x4 u1 = *(const f32x4*)(xp + 4);
    float v[8] = {u0[0], u0[1], u0[2], u0[3], u1[0], u1[1], u1[2], u1[3]};
    f16x8 bh, bl;
#pragma unroll
    for (int p = 0; p < 8; ++p) {
      float f = v[p] * 256.f;
      f16 h1 = (f16)f;
      bh[p] = h1;
      bl[p] = (f16)(f - (float)h1);
    }
    f16x8 b1 = (g < 2) ? bh : bl;
    f16x8 b2 = (g < 2) ? bl : bh;
    acc = __builtin_amdgcn_mfma_f32_16x16x32_f16(aw[st], b1, acc, 0, 0, 0);
    acc = __builtin_amdgcn_mfma_f32_16x16x32_f16(aw[st], b2, acc, 0, 0, 0);
  }
  *(f32x4*)&comb[w * 320 + col * 20 + g * 4] = acc;
  __syncthreads();

  // ---------------- LayerNorm (scaled; exact ratio) ----------------
  const int tokL = tid >> 4;
  const int cL = tid & 15;
  const int jL = tokL >> 4;
  const int colL = tokL & 15;
  float hv = (comb[(0 * 4 + jL) * 320 + colL * 20 + cL] +
              comb[(1 * 4 + jL) * 320 + colL * 20 + cL]) +
             (comb[(2 * 4 + jL) * 320 + colL * 20 + cL] +
              comb[(3 * 4 + jL) * 320 + colL * 20 + cL]);
  float s = hv;
  s += __shfl_xor(s, 1, 16);
  s += __shfl_xor(s, 2, 16);
  s += __shfl_xor(s, 4, 16);
  s += __shfl_xor(s, 8, 16);
  float mu = s * (1.f / 16.f);
  float diff = hv - mu;
  float v2 = diff * diff;
  v2 += __shfl_xor(v2, 1, 16);
  v2 += __shfl_xor(v2, 2, 16);
  v2 += __shfl_xor(v2, 4, 16);
  v2 += __shfl_xor(v2, 8, 16);
  float var = v2 * (1.f / 16.f);
  hsm[tokL][cL] = diff / sqrtf(var + EPS_S);   // unscaled normalized h
  __syncthreads();

  // ---------------- build B fragments for 4 tiles ----------------
  f16x8 b1[4], b2[4];
#pragma unroll
  for (int jj = 0; jj < 4; ++jj) {
#pragma unroll
    for (int p = 0; p < 8; ++p) {
      float f = hsm[jj * 16 + col][doff + p] * 256.f;
      f16 h1 = (f16)f;
      f16 l1 = (f16)(f - (float)h1);
      b1[jj][p] = (g < 2) ? h1 : l1;
      b2[jj][p] = (g < 2) ? l1 : h1;
    }
  }

  // ---------------- phase B: argmin sweep ----------------
  const int q = w;                   // this wave's K-slice (512 codes)
  float best[4] = {3.0e38f, 3.0e38f, 3.0e38f, 3.0e38f};
  int btg[4] = {0, 0, 0, 0};

#pragma unroll 4
  for (int t = 0; t < 32; ++t) {
    const int ktile = q * 32 + t;
    f16x8 a = *(const f16x8*)&cbA[((size_t)ktile * 64 + lane) * 8];
    f32x4 c2v = *(const f32x4*)&c2s[ktile * 16 + g * 4];
    const int tag = t * 4 + g;       // (t,g) packed; ordering == k ordering
#pragma unroll
    for (int jj = 0; jj < 4; ++jj) {
      f32x4 ac = __builtin_amdgcn_mfma_f32_16x16x32_f16(a, b1[jj], c2v, 0, 0, 0);
      ac = __builtin_amdgcn_mfma_f32_16x16x32_f16(a, b2[jj], ac, 0, 0, 0);
      float m = fminf(fminf(ac[0], ac[1]), fminf(ac[2], ac[3]));
      bool lt = m < best[jj];        // strict <: earliest t wins ties
      best[jj] = lt ? m : best[jj];
      btg[jj] = lt ? tag : btg[jj];
    }
  }

  // merge the 4 lane-groups per token; store per-q result
#pragma unroll
  for (int jj = 0; jj < 4; ++jj) {
    float d = best[jj];
    int tg = btg[jj];
#pragma unroll
    for (int off = 16; off <= 32; off <<= 1) {
      float od = __shfl_xor(d, off);
      int otg = __shfl_xor(tg, off);
      bool take = (od < d) || (od == d && otg < tg);
      d = take ? od : d;
      tg = take ? otg : tg;
    }
    if (lane < 16) {
      fin_d[q][jj * 16 + lane] = d;
      fin_t[q][jj * 16 + lane] = tg;
    }
  }
  __syncthreads();

  // ---------------- finalize: merge q's + disambiguate ----------------
  if (tid < 64) {
    const int tok = tid;
    float bd = fin_d[0][tok];
    int btag = fin_t[0][tok];
    int bq = 0;
#pragma unroll
    for (int q2 = 1; q2 < 16; ++q2) {
      float d2 = fin_d[q2][tok];
      int t2 = fin_t[q2][tok];
      bool take = (d2 < bd) || (d2 == bd && false);  // ascending q: strict <
      bd = take ? d2 : bd;
      btag = take ? t2 : btag;
      bq = take ? q2 : bq;
    }
    const int k0 = bq * 512 + (btag >> 2) * 16 + (btag & 3) * 4;

    float h[16];
#pragma unroll
    for (int dd = 0; dd < 16; ++dd) h[dd] = hsm[tok][dd];

    float bestd = 3.0e38f;
    int bestk = k0;
#pragma unroll
    for (int r = 0; r < 4; ++r) {
      const int kk = k0 + r;
      const float* crow = cb + (size_t)kk * DC;
      float sd = 0.f;
#pragma unroll
      for (int dd = 0; dd < 16; ++dd) {
        float df = h[dd] - crow[dd];
        sd = fmaf(df, df, sd);
      }
      if (sd < bestd) {              // strict <: lowest r (lowest k) on ties
        bestd = sd;
        bestk = kk;
      }
    }
    out[tb + tok] = bestk;
  }
}

// ---------------------------------------------------------------------------
extern "C" void kernel_launch(void* const* d_in, const int* in_sizes, int n_in,
                              void* d_out, int out_size, void* d_ws,
                              size_t ws_size, hipStream_t stream) {
  const float* x = (const float*)d_in[0];    // (8,2048,512)
  const float* w = (const float*)d_in[1];    // (16,512)
  const float* cb = (const float*)d_in[2];   // (8192,16)

  f16* cbA = (f16*)d_ws;                        // 8192*32 halves = 512 KB
  float* c2s = (float*)(cbA + (size_t)K * 32);  // 32 KB

  prep_cb<<<K / 64, 256, 0, stream>>>(cb, cbA, c2s);
  fused<<<NTOK / 64, 1024, 0, stream>>>(x, w, cb, cbA, c2s, (int*)d_out);
}

// Round 9
// 40.433 us; speedup vs baseline: 1.1944x; 1.1218x over previous
//
#include <hip/hip_runtime.h>
#include <math.h>

#define LN_EPS 1e-5f

typedef _Float16 f16;
typedef _Float16 f16x8 __attribute__((ext_vector_type(8)));
typedef _Float16 f16x2 __attribute__((ext_vector_type(2)));
typedef __fp16 fp16x2 __attribute__((ext_vector_type(2)));
typedef float f32x4 __attribute__((ext_vector_type(4)));

constexpr int DC = 16;
constexpr int K = 8192;
constexpr int NTOK = 16384;        // 8*2048
constexpr int D = 512;
constexpr float SCALE = 16384.f;   // 256 * 64, exact powers of 2
constexpr float EPS_S = LN_EPS * SCALE * SCALE;

static __device__ __forceinline__ f16x8 mk8(f16x2 a, f16x2 b, f16x2 c,
                                            f16x2 d) {
  union {
    f16x2 p[4];
    f16x8 v;
  } u;
  u.p[0] = a;
  u.p[1] = b;
  u.p[2] = c;
  u.p[3] = d;
  return u.v;
}

// hi = f32 masked to 11-bit mantissa (exactly representable in f16; pkrtz is
// then exact), lo = residual (pkrtz rounds, err <= 2^-23 * |v| total).
static __device__ __forceinline__ void hilo2(float f0, float f1, f16x2& ph,
                                             f16x2& pl) {
  float h0 = __uint_as_float(__float_as_uint(f0) & 0xFFFFE000u);
  float h1 = __uint_as_float(__float_as_uint(f1) & 0xFFFFE000u);
  ph = __builtin_bit_cast(f16x2, __builtin_amdgcn_cvt_pkrtz(h0, h1));
  pl = __builtin_bit_cast(f16x2,
                          __builtin_amdgcn_cvt_pkrtz(f0 - h0, f1 - h1));
}

// ---------------------------------------------------------------------------
// prep: blocks [0,128): codebook -> cbA A-frags (x -128, hi/lo) + biased c2.
//       block 128: W -> wAf A-frags (x 64, hi/lo), 32 tiles (dq*8+st).
// Frag per 16-row tile: lane l holds 8 halves, slots s=(l>>4)*8+p;
// s<16 -> hi(dim s), s>=16 -> lo(dim s-16). Rows = l&15.
// ---------------------------------------------------------------------------
__global__ __launch_bounds__(256) void prep(const float* __restrict__ cb,
                                            const float* __restrict__ wq,
                                            f16* __restrict__ cbA,
                                            float* __restrict__ c2s,
                                            f16* __restrict__ wAf) {
  const int tid = threadIdx.x;

  if (blockIdx.x == K / 64) {
    // ---- W fragments: 2048 (tile,lane) slots, 8 per thread ----
#pragma unroll
    for (int i = 0; i < 8; ++i) {
      int slot = tid + 256 * i;
      int tile = slot >> 6;          // dq*8+st ; dim base = tile*16
      int l = slot & 63;
      int g = l >> 4;
      int col = l & 15;              // c_out row
      int doff = (g & 1) * 8;
      const float* wp = wq + (size_t)col * D + tile * 16 + doff;
      f32x4 u0 = *(const f32x4*)wp;
      f32x4 u1 = *(const f32x4*)(wp + 4);
      f16x2 ph[4], pl[4];
      hilo2(u0[0] * 64.f, u0[1] * 64.f, ph[0], pl[0]);
      hilo2(u0[2] * 64.f, u0[3] * 64.f, ph[1], pl[1]);
      hilo2(u1[0] * 64.f, u1[1] * 64.f, ph[2], pl[2]);
      hilo2(u1[2] * 64.f, u1[3] * 64.f, ph[3], pl[3]);
      f16x8 hi = mk8(ph[0], ph[1], ph[2], ph[3]);
      f16x8 lo = mk8(pl[0], pl[1], pl[2], pl[3]);
      *(f16x8*)(wAf + (size_t)slot * 8) = (g < 2) ? hi : lo;
    }
    return;
  }

  // ---- codebook: 4 code-tiles per block ----
  const int ti = tid >> 6;
  const int l = tid & 63;
  const int ct = blockIdx.x * 4 + ti;
  const int code = ct * 16 + (l & 15);
  const int g = l >> 4;

  const float* row = cb + (size_t)code * DC + (g & 1) * 8;
  f32x4 v0 = *(const f32x4*)row;
  f32x4 v1 = *(const f32x4*)(row + 4);
  f16x2 ph[4], pl[4];
  hilo2(v0[0] * -128.f, v0[1] * -128.f, ph[0], pl[0]);
  hilo2(v0[2] * -128.f, v0[3] * -128.f, ph[1], pl[1]);
  hilo2(v1[0] * -128.f, v1[1] * -128.f, ph[2], pl[2]);
  hilo2(v1[2] * -128.f, v1[3] * -128.f, ph[3], pl[3]);
  f16x8 hi = mk8(ph[0], ph[1], ph[2], ph[3]);
  f16x8 lo = mk8(pl[0], pl[1], pl[2], pl[3]);
  *(f16x8*)(cbA + ((size_t)ct * 64 + l) * 8) = (g < 2) ? hi : lo;

  if (g == 0) {
    const f32x4* rw = (const f32x4*)(cb + (size_t)code * DC);
    f32x4 a0 = rw[0], a1 = rw[1], a2 = rw[2], a3 = rw[3];
    float s = 0.f;
#pragma unroll
    for (int p = 0; p < 4; ++p)
      s += a0[p] * a0[p] + a1[p] * a1[p] + a2[p] * a2[p] + a3[p] * a3[p];
    c2s[code] = (s + 16.5f) * SCALE;   // +16.5 > h2=16 keeps dist > 0
  }
}

// ---------------------------------------------------------------------------
// fused: 512 blocks x 512 thr (2 blocks/CU -> barrier/latency overlap).
// Block owns 32 tokens. Phase A: wave (j=w&1 tile, dq=w>>1 D-quarter):
// x direct from global, W frags preloaded, 16 MFMA -> partial C; combine via
// LDS; LN width-16 shfl (scaled, EPS_S). Phase B: wave w sweeps codes
// [w*1024,(w+1)*1024) for both tiles; tag-free running min (fminf tree) +
// per-8-iter group tag. Merge lane-groups/waves by (dist, k-ordered tag);
// winning 32-code group disambiguated by exact fp32 recompute with 16
// threads/token. Output straight to d_out.
// ---------------------------------------------------------------------------
__global__ __launch_bounds__(512, 4) void fused(
    const float* __restrict__ x, const float* __restrict__ cb,
    const f16* __restrict__ cbA, const float* __restrict__ c2s,
    const f16* __restrict__ wAf, int* __restrict__ out) {
  __shared__ float comb[8 * 16 * 20];   // 10.2 KB [w][col][20]
  __shared__ float hsm[32 * 20];        // 2.6 KB  [tok][20]
  __shared__ float fin_d[8][32];        // 1 KB
  __shared__ int fin_t[8][32];          // 1 KB

  const int tid = threadIdx.x;
  const int w = tid >> 6;
  const int lane = tid & 63;
  const int g = lane >> 4;
  const int col = lane & 15;
  const int doff = (g & 1) * 8;
  const int tb = blockIdx.x * 32;

  // ---------------- phase A ----------------
  const int j = w & 1;
  const int dq = w >> 1;

  // x loads first (L3/HBM latency overlaps wAf loads + conversion)
  const float* xrow = x + (size_t)(tb + j * 16 + col) * D + dq * 128 + doff;
  f32x4 xu0[8], xu1[8];
#pragma unroll
  for (int st = 0; st < 8; ++st) {
    xu0[st] = *(const f32x4*)(xrow + st * 16);
    xu1[st] = *(const f32x4*)(xrow + st * 16 + 4);
  }
  f16x8 aw[8];
#pragma unroll
  for (int st = 0; st < 8; ++st)
    aw[st] = *(const f16x8*)(wAf + ((size_t)(dq * 8 + st) * 64 + lane) * 8);

  f32x4 acc = {0.f, 0.f, 0.f, 0.f};
#pragma unroll
  for (int st = 0; st < 8; ++st) {
    f16x2 ph[4], pl[4];
    hilo2(xu0[st][0] * 256.f, xu0[st][1] * 256.f, ph[0], pl[0]);
    hilo2(xu0[st][2] * 256.f, xu0[st][3] * 256.f, ph[1], pl[1]);
    hilo2(xu1[st][0] * 256.f, xu1[st][1] * 256.f, ph[2], pl[2]);
    hilo2(xu1[st][2] * 256.f, xu1[st][3] * 256.f, ph[3], pl[3]);
    f16x8 bh = mk8(ph[0], ph[1], ph[2], ph[3]);
    f16x8 bl = mk8(pl[0], pl[1], pl[2], pl[3]);
    f16x8 b1 = (g < 2) ? bh : bl;
    f16x8 b2 = (g < 2) ? bl : bh;
    acc = __builtin_amdgcn_mfma_f32_16x16x32_f16(aw[st], b1, acc, 0, 0, 0);
    acc = __builtin_amdgcn_mfma_f32_16x16x32_f16(aw[st], b2, acc, 0, 0, 0);
  }
  *(f32x4*)&comb[(w * 16 + col) * 20 + g * 4] = acc;
  __syncthreads();

  // ---------------- LayerNorm (scaled values; exact ratio) ----------------
  const int tokL = tid >> 4;           // 0..31
  const int cL = tid & 15;
  const int jL = tokL >> 4;
  const int colL = tokL & 15;
  float hv = (comb[((0 * 2 + jL) * 16 + colL) * 20 + cL] +
              comb[((1 * 2 + jL) * 16 + colL) * 20 + cL]) +
             (comb[((2 * 2 + jL) * 16 + colL) * 20 + cL] +
              comb[((3 * 2 + jL) * 16 + colL) * 20 + cL]);
  float s = hv;
  s += __shfl_xor(s, 1, 16);
  s += __shfl_xor(s, 2, 16);
  s += __shfl_xor(s, 4, 16);
  s += __shfl_xor(s, 8, 16);
  float mu = s * (1.f / 16.f);
  float diff = hv - mu;
  float v2 = diff * diff;
  v2 += __shfl_xor(v2, 1, 16);
  v2 += __shfl_xor(v2, 2, 16);
  v2 += __shfl_xor(v2, 4, 16);
  v2 += __shfl_xor(v2, 8, 16);
  float var = v2 * (1.f / 16.f);
  hsm[tokL * 20 + cL] = diff / sqrtf(var + EPS_S);   // unscaled LN'd h
  __syncthreads();

  // ---------------- phase B: B frags for the 2 tiles ----------------
  f16x8 b1[2], b2[2];
#pragma unroll
  for (int jj = 0; jj < 2; ++jj) {
    const float* hp = &hsm[(jj * 16 + col) * 20 + doff];
    f32x4 u0 = *(const f32x4*)hp;
    f32x4 u1 = *(const f32x4*)(hp + 4);
    f16x2 ph[4], pl[4];
    hilo2(u0[0] * 256.f, u0[1] * 256.f, ph[0], pl[0]);
    hilo2(u0[2] * 256.f, u0[3] * 256.f, ph[1], pl[1]);
    hilo2(u1[0] * 256.f, u1[1] * 256.f, ph[2], pl[2]);
    hilo2(u1[2] * 256.f, u1[3] * 256.f, ph[3], pl[3]);
    f16x8 bh = mk8(ph[0], ph[1], ph[2], ph[3]);
    f16x8 bl = mk8(pl[0], pl[1], pl[2], pl[3]);
    b1[jj] = (g < 2) ? bh : bl;
    b2[jj] = (g < 2) ? bl : bh;
  }

  // ---------------- phase B: sweep (tag-free min + group tags) ----------
  const int q = w;                     // K-slice [q*1024, (q+1)*1024)
  float best0 = 3.0e38f, best1 = 3.0e38f;
  int grp0 = 0, grp1 = 0;
  const f16* pa = cbA + ((size_t)q * 64 * 64 + lane) * 8;
  const float* pc = c2s + q * 1024 + g * 4;

  for (int gi = 0; gi < 8; ++gi) {
    float sb0 = best0, sb1 = best1;
#pragma unroll
    for (int ti = 0; ti < 8; ++ti) {
      int t = gi * 8 + ti;
      f16x8 a = *(const f16x8*)(pa + (size_t)t * 512);
      f32x4 c2v = *(const f32x4*)(pc + t * 16);
      f32x4 a0 = __builtin_amdgcn_mfma_f32_16x16x32_f16(a, b1[0], c2v, 0, 0, 0);
      a0 = __builtin_amdgcn_mfma_f32_16x16x32_f16(a, b2[0], a0, 0, 0, 0);
      f32x4 a1 = __builtin_amdgcn_mfma_f32_16x16x32_f16(a, b1[1], c2v, 0, 0, 0);
      a1 = __builtin_amdgcn_mfma_f32_16x16x32_f16(a, b2[1], a1, 0, 0, 0);
      best0 = fminf(best0, fminf(fminf(a0[0], a0[1]), fminf(a0[2], a0[3])));
      best1 = fminf(best1, fminf(fminf(a1[0], a1[1]), fminf(a1[2], a1[3])));
    }
    grp0 = (best0 < sb0) ? gi : grp0;  // strict <: earliest group on ties
    grp1 = (best1 < sb1) ? gi : grp1;
  }

  // merge lane-groups per tile; tag = grp*4+g (k-ordered: grp major)
  int tg0 = grp0 * 4 + g, tg1 = grp1 * 4 + g;
#pragma unroll
  for (int off = 16; off <= 32; off <<= 1) {
    float od = __shfl_xor(best0, off);
    int ot = __shfl_xor(tg0, off);
    bool tk = (od < best0) || (od == best0 && ot < tg0);
    best0 = tk ? od : best0;
    tg0 = tk ? ot : tg0;
    od = __shfl_xor(best1, off);
    ot = __shfl_xor(tg1, off);
    tk = (od < best1) || (od == best1 && ot < tg1);
    best1 = tk ? od : best1;
    tg1 = tk ? ot : tg1;
  }
  if (lane < 16) {
    fin_d[q][lane] = best0;
    fin_t[q][lane] = tg0;
    fin_d[q][16 + lane] = best1;
    fin_t[q][16 + lane] = tg1;
  }
  __syncthreads();

  // ---------------- finalize: 16 threads/token, 32-code exact verify ------
  const int tok = tid >> 4;
  const int c = tid & 15;
  float bd = fin_d[0][tok];
  int btag = fin_t[0][tok];
  int bq = 0;
#pragma unroll
  for (int q2 = 1; q2 < 8; ++q2) {
    float d2 = fin_d[q2][tok];
    int t2 = fin_t[q2][tok];
    bool tk = d2 < bd;                 // ascending q: strict <
    bd = tk ? d2 : bd;
    btag = tk ? t2 : btag;
    bq = tk ? q2 : bq;
  }
  const int kb = bq * 1024 + (btag >> 2) * 128 + (btag & 3) * 4;

  f32x4 h0 = *(const f32x4*)&hsm[tok * 20];
  f32x4 h1 = *(const f32x4*)&hsm[tok * 20 + 4];
  f32x4 h2 = *(const f32x4*)&hsm[tok * 20 + 8];
  f32x4 h3 = *(const f32x4*)&hsm[tok * 20 + 12];

  float bestd = 3.0e38f;
  int bestk = kb;
#pragma unroll
  for (int e2 = 0; e2 < 2; ++e2) {
    int e = c * 2 + e2;                // e ascending == k ascending
    int kk = kb + (e >> 2) * 16 + (e & 3);
    const f32x4* cr = (const f32x4*)(cb + (size_t)kk * DC);
    f32x4 c0 = cr[0], c1 = cr[1], c2r = cr[2], c3 = cr[3];
    float sd = 0.f;
#pragma unroll
    for (int p = 0; p < 4; ++p) {
      float d0 = h0[p] - c0[p];
      float d1 = h1[p] - c1[p];
      float dd2 = h2[p] - c2r[p];
      float d3 = h3[p] - c3[p];
      sd = fmaf(d0, d0, sd);
      sd = fmaf(d1, d1, sd);
      sd = fmaf(dd2, dd2, sd);
      sd = fmaf(d3, d3, sd);
    }
    bool tk = sd < bestd;
    bestd = tk ? sd : bestd;
    bestk = tk ? kk : bestk;
  }
#pragma unroll
  for (int off = 1; off < 16; off <<= 1) {
    float od = __shfl_xor(bestd, off, 16);
    int ok = __shfl_xor(bestk, off, 16);
    bool tk = (od < bestd) || (od == bestd && ok < bestk);
    bestd = tk ? od : bestd;
    bestk = tk ? ok : bestk;
  }
  if (c == 0) out[tb + tok] = bestk;
}

// ---------------------------------------------------------------------------
extern "C" void kernel_launch(void* const* d_in, const int* in_sizes, int n_in,
                              void* d_out, int out_size, void* d_ws,
                              size_t ws_size, hipStream_t stream) {
  const float* x = (const float*)d_in[0];    // (8,2048,512)
  const float* w = (const float*)d_in[1];    // (16,512)
  const float* cb = (const float*)d_in[2];   // (8192,16)

  f16* cbA = (f16*)d_ws;                        // 512 KB
  float* c2s = (float*)(cbA + (size_t)K * 32);  // 32 KB
  f16* wAf = (f16*)(c2s + K);                   // 32 KB

  prep<<<K / 64 + 1, 256, 0, stream>>>(cb, w, cbA, c2s, wAf);
  fused<<<NTOK / 32, 512, 0, stream>>>(x, cb, cbA, c2s, wAf, (int*)d_out);
}